// Round 1
// baseline (662.924 us; speedup 1.0000x reference)
//
#include <hip/hip_runtime.h>
#include <hip/hip_bf16.h>

typedef short bf16x8 __attribute__((ext_vector_type(8)));
typedef float f32x4 __attribute__((ext_vector_type(4)));

#define TILE 128
#define BK 32
#define SCH 128

__device__ __forceinline__ float bf2f(short u) {
  return __uint_as_float(((unsigned int)(unsigned short)u) << 16);
}
__device__ __forceinline__ unsigned short f2bf(float f) {
  unsigned int u = __float_as_uint(f);
  u = u + 0x7FFFu + ((u >> 16) & 1u);   // RNE
  return (unsigned short)(u >> 16);
}

// ---------------- convert fp32 -> bf16 (vectorized, 8 elems/thread) ----------------
__global__ __launch_bounds__(256)
void cvt_f32_bf16(const float* __restrict__ in, unsigned short* __restrict__ out, int n8) {
  int i = blockIdx.x * 256 + threadIdx.x;
  if (i >= n8) return;
  const float4* p = (const float4*)in + (size_t)i * 2;
  float4 a = p[0], b = p[1];
  bf16x8 o;
  o[0] = (short)f2bf(a.x); o[1] = (short)f2bf(a.y); o[2] = (short)f2bf(a.z); o[3] = (short)f2bf(a.w);
  o[4] = (short)f2bf(b.x); o[5] = (short)f2bf(b.y); o[6] = (short)f2bf(b.z); o[7] = (short)f2bf(b.w);
  *((bf16x8*)out + i) = o;
}

// ---------------- transpose + convert: in[K][N] f32 -> out[N][K] bf16 ----------------
__global__ __launch_bounds__(256)
void tcvt(const float* __restrict__ in, unsigned short* __restrict__ out, int K, int N) {
  __shared__ float t[32][33];
  int n0 = blockIdx.x * 32, k0 = blockIdx.y * 32;
  int tx = threadIdx.x & 31, ty = threadIdx.x >> 5;   // 32 x 8
#pragma unroll
  for (int j = 0; j < 4; ++j)
    t[ty + 8 * j][tx] = in[(size_t)(k0 + ty + 8 * j) * N + n0 + tx];
  __syncthreads();
#pragma unroll
  for (int j = 0; j < 4; ++j)
    out[(size_t)(n0 + ty + 8 * j) * K + k0 + tx] = f2bf(t[tx][ty + 8 * j]);
}

// ---------------- bf16 MFMA GEMM, C = A(MxK) * Bt(NxK)^T ; m97 128^2 structure ----------------
// EPI=0: store bf16, apply elu+1 to cols < eluCols (q,k sections)
// EPI=1: store f32 + bias
template <int EPI>
__global__ __launch_bounds__(256)
void gemm_bt(const unsigned short* __restrict__ A, const unsigned short* __restrict__ Bt,
             void* __restrict__ Cout, const float* __restrict__ bias,
             int M, int N, int K, int eluCols) {
  __shared__ __align__(16) unsigned short As[TILE * BK];
  __shared__ __align__(16) unsigned short Bs[TILE * BK];
  const int tid = threadIdx.x;
  const int wid = tid >> 6, lane = tid & 63;
  const int wr = wid >> 1, wc = wid & 1;          // 2x2 wave grid, 64x64 each
  const int fr = lane & 15, fq = lane >> 4;
  const int rowA0 = blockIdx.y * TILE;
  const int rowB0 = blockIdx.x * TILE;
  const int srow = lane >> 2, scol = (lane & 3) << 3;

  f32x4 acc[4][4];
#pragma unroll
  for (int i = 0; i < 4; ++i)
#pragma unroll
    for (int j = 0; j < 4; ++j) acc[i][j] = (f32x4)(0.f);

  const unsigned short* gA = A + (size_t)(rowA0 + wid * 32 + srow) * K + scol;
  const unsigned short* gB = Bt + (size_t)(rowB0 + wid * 32 + srow) * K + scol;
  unsigned short* lA = &As[(wid * 32) * BK];
  unsigned short* lB = &Bs[(wid * 32) * BK];

  for (int kt = 0; kt < K; kt += BK) {
    __builtin_amdgcn_global_load_lds((const __attribute__((address_space(1))) void*)(gA + kt),
                                     (__attribute__((address_space(3))) void*)lA, 16, 0, 0);
    __builtin_amdgcn_global_load_lds((const __attribute__((address_space(1))) void*)(gA + kt + (size_t)16 * K),
                                     (__attribute__((address_space(3))) void*)(lA + 16 * BK), 16, 0, 0);
    __builtin_amdgcn_global_load_lds((const __attribute__((address_space(1))) void*)(gB + kt),
                                     (__attribute__((address_space(3))) void*)lB, 16, 0, 0);
    __builtin_amdgcn_global_load_lds((const __attribute__((address_space(1))) void*)(gB + kt + (size_t)16 * K),
                                     (__attribute__((address_space(3))) void*)(lB + 16 * BK), 16, 0, 0);
    __syncthreads();
    bf16x8 a[4], b[4];
#pragma unroll
    for (int i = 0; i < 4; ++i)
      a[i] = *(const bf16x8*)&As[(wr * 64 + i * 16 + fr) * BK + fq * 8];
#pragma unroll
    for (int j = 0; j < 4; ++j)
      b[j] = *(const bf16x8*)&Bs[(wc * 64 + j * 16 + fr) * BK + fq * 8];
#pragma unroll
    for (int i = 0; i < 4; ++i)
#pragma unroll
      for (int j = 0; j < 4; ++j)
        acc[i][j] = __builtin_amdgcn_mfma_f32_16x16x32_bf16(a[i], b[j], acc[i][j], 0, 0, 0);
    __syncthreads();
  }

  // epilogue: D row = (lane>>4)*4 + r, col = lane&15  [m89-verified layout]
  if (EPI == 0) {
    unsigned short* Cb = (unsigned short*)Cout;
#pragma unroll
    for (int j = 0; j < 4; ++j) {
      int col = rowB0 + wc * 64 + j * 16 + fr;
      bool elu = col < eluCols;
#pragma unroll
      for (int i = 0; i < 4; ++i) {
        int row0 = rowA0 + wr * 64 + i * 16 + fq * 4;
#pragma unroll
        for (int r = 0; r < 4; ++r) {
          float x = acc[i][j][r];
          if (elu) x = x > 0.f ? x + 1.f : __expf(x);   // elu(x)+1
          Cb[(size_t)(row0 + r) * N + col] = f2bf(x);
        }
      }
    }
  } else {
    float* Cf = (float*)Cout;
#pragma unroll
    for (int j = 0; j < 4; ++j) {
      int col = rowB0 + wc * 64 + j * 16 + fr;
      float bv = bias[col];
#pragma unroll
      for (int i = 0; i < 4; ++i) {
        int row0 = rowA0 + wr * 64 + i * 16 + fq * 4;
#pragma unroll
        for (int r = 0; r < 4; ++r)
          Cf[(size_t)(row0 + r) * N + col] = acc[i][j][r] + bv;
      }
    }
  }
}

// ---------------- kv[b,h,d,e] = sum_s k[s,d]*v[s,e]; ksum[b,h,d] = sum_s k[s,d] ----------------
__global__ __launch_bounds__(256)
void kv_accum(const unsigned short* __restrict__ qkv, float* __restrict__ kv_out,
              float* __restrict__ ksum) {
  const int bh = blockIdx.x;
  const int b = bh / 12, h = bh - b * 12;
  const int s0 = blockIdx.y * SCH;
  __shared__ __align__(16) float ks[SCH][64];
  __shared__ __align__(16) float vs[SCH][64];
  const size_t rowbase = (size_t)(b * 4096 + s0) * 2304;
  const unsigned short* kg = qkv + rowbase + 768 + h * 64;
  const unsigned short* vg = qkv + rowbase + 1536 + h * 64;
  for (int i = threadIdx.x; i < SCH * 8; i += 256) {
    int s = i >> 3, dc = (i & 7) << 3;
    bf16x8 k8 = *(const bf16x8*)(kg + (size_t)s * 2304 + dc);
    bf16x8 v8 = *(const bf16x8*)(vg + (size_t)s * 2304 + dc);
#pragma unroll
    for (int j = 0; j < 8; ++j) {
      ks[s][dc + j] = bf2f(k8[j]);
      vs[s][dc + j] = bf2f(v8[j]);
    }
  }
  __syncthreads();
  const int td = threadIdx.x >> 4, te = threadIdx.x & 15;   // 4x4 register tile
  float acc[4][4] = {};
  float ksl[4] = {};
#pragma unroll 4
  for (int s = 0; s < SCH; ++s) {
    f32x4 ka = *(const f32x4*)&ks[s][td * 4];
    f32x4 va = *(const f32x4*)&vs[s][te * 4];
#pragma unroll
    for (int i = 0; i < 4; ++i) {
      ksl[i] += ka[i];
#pragma unroll
      for (int j = 0; j < 4; ++j) acc[i][j] += ka[i] * va[j];
    }
  }
  float* kvp = kv_out + ((size_t)bh * 64 + td * 4) * 64 + te * 4;
#pragma unroll
  for (int i = 0; i < 4; ++i)
#pragma unroll
    for (int j = 0; j < 4; ++j) atomicAdd(&kvp[(size_t)i * 64 + j], acc[i][j]);
  if (te == 0) {
#pragma unroll
    for (int i = 0; i < 4; ++i) atomicAdd(&ksum[bh * 64 + td * 4 + i], ksl[i]);
  }
}

// ---------------- attn[b,s,h*64+e] = z * sum_d q[s,d]*kv[d,e];  z = 1/sum_d q[s,d]*ksum[d] ----------------
__global__ __launch_bounds__(256)
void attn_out(const unsigned short* __restrict__ qkv, const float* __restrict__ kv,
              const float* __restrict__ ksum, unsigned short* __restrict__ attn) {
  const int bh = blockIdx.x;
  const int b = bh / 12, h = bh - b * 12;
  const int s0 = blockIdx.y * 64;
  __shared__ __align__(16) float kvs[64][64];
  __shared__ float kss[64];
  {
    const float4* kvg = (const float4*)(kv + (size_t)bh * 4096);
    float4* kvl = (float4*)&kvs[0][0];
    for (int i = threadIdx.x; i < 1024; i += 256) kvl[i] = kvg[i];
    if (threadIdx.x < 64) kss[threadIdx.x] = ksum[bh * 64 + threadIdx.x];
  }
  __syncthreads();
  const int tr = threadIdx.x >> 2;    // row 0..63
  const int te = threadIdx.x & 3;     // 16-col slab
  const int s = s0 + tr;
  const unsigned short* qg = qkv + (size_t)(b * 4096 + s) * 2304 + h * 64;
  bf16x8 q8[8];
#pragma unroll
  for (int c = 0; c < 8; ++c) q8[c] = *(const bf16x8*)(qg + c * 8);
  float acc[16] = {};
  float zz = 0.f;
#pragma unroll
  for (int c = 0; c < 8; ++c) {
#pragma unroll
    for (int j = 0; j < 8; ++j) {
      const int d = c * 8 + j;
      const float qd = bf2f(q8[c][j]);
      zz += qd * kss[d];
      const f32x4* kvr = (const f32x4*)&kvs[d][te * 16];
#pragma unroll
      for (int q4 = 0; q4 < 4; ++q4) {
        f32x4 kk = kvr[q4];
        acc[q4 * 4 + 0] += qd * kk[0];
        acc[q4 * 4 + 1] += qd * kk[1];
        acc[q4 * 4 + 2] += qd * kk[2];
        acc[q4 * 4 + 3] += qd * kk[3];
      }
    }
  }
  const float z = 1.f / zz;
  bf16x8 o0, o1;
#pragma unroll
  for (int j = 0; j < 8; ++j) o0[j] = (short)f2bf(acc[j] * z);
#pragma unroll
  for (int j = 0; j < 8; ++j) o1[j] = (short)f2bf(acc[8 + j] * z);
  unsigned short* og = attn + (size_t)(b * 4096 + s) * 768 + h * 64 + te * 16;
  *(bf16x8*)og = o0;
  *(bf16x8*)(og + 8) = o1;
}

extern "C" void kernel_launch(void* const* d_in, const int* in_sizes, int n_in,
                              void* d_out, int out_size, void* d_ws, size_t ws_size,
                              hipStream_t stream) {
  const float* x      = (const float*)d_in[0];
  const float* w_qkv  = (const float*)d_in[1];
  const float* w_proj = (const float*)d_in[2];
  const float* b_proj = (const float*)d_in[3];
  const int B = 8, N = 4096, C = 768, H = 12, D = 64;
  const int M = B * N;      // 32768
  const int N1 = 3 * C;     // 2304

  char* ws = (char*)d_ws;
  unsigned short* xb     = (unsigned short*)(ws);               // 50,331,648 B (reused for attn out)
  unsigned short* wqkvT  = (unsigned short*)(ws + 50331648);    //  3,538,944 B
  unsigned short* wprojT = (unsigned short*)(ws + 53870592);    //  1,179,648 B
  float*          ksum   = (float*)(ws + 55050240);             //     24,576 B
  unsigned short* qkvb   = (unsigned short*)(ws + 55074816);    // 150,994,944 B  (total ~206 MB)

  float* out_main = (float*)d_out;
  float* kv_out   = out_main + (size_t)M * C;   // kv output: (B,H,D,D) f32

  hipMemsetAsync(kv_out, 0, (size_t)B * H * D * D * sizeof(float), stream);
  hipMemsetAsync(ksum, 0, (size_t)B * H * D * sizeof(float), stream);

  cvt_f32_bf16<<<(M * C / 8 + 255) / 256, 256, 0, stream>>>(x, xb, M * C / 8);
  tcvt<<<dim3(N1 / 32, C / 32), 256, 0, stream>>>(w_qkv, wqkvT, C, N1);
  tcvt<<<dim3(C / 32, C / 32), 256, 0, stream>>>(w_proj, wprojT, C, C);

  // qkv = x @ w_qkv, with elu+1 applied to q,k sections (cols < 1536), stored bf16
  gemm_bt<0><<<dim3(N1 / TILE, M / TILE), 256, 0, stream>>>(xb, wqkvT, qkvb, nullptr, M, N1, C, 2 * C);

  // global kv + ksum accumulation (fp32 atomics into zeroed buffers)
  kv_accum<<<dim3(B * H, N / SCH), 256, 0, stream>>>(qkvb, kv_out, ksum);

  // out_attn = (q @ kv) * z, stored bf16 into xb (x no longer needed)
  attn_out<<<dim3(B * H, N / 64), 256, 0, stream>>>(qkvb, kv_out, ksum, xb);

  // out = attn @ w_proj + b_proj, fp32 into d_out
  gemm_bt<1><<<dim3(C / TILE, M / TILE), 256, 0, stream>>>(xb, wprojT, d_out, b_proj, M, C, C, 0);
}

// Round 2
// 634.297 us; speedup vs baseline: 1.0451x; 1.0451x over previous
//
#include <hip/hip_runtime.h>
#include <hip/hip_bf16.h>

typedef short bf16x8 __attribute__((ext_vector_type(8)));
typedef float f32x4 __attribute__((ext_vector_type(4)));

#define SCH 128
#define MFMA_BF16 __builtin_amdgcn_mfma_f32_16x16x32_bf16
#define BARRIER() asm volatile("s_barrier" ::: "memory")

__device__ __forceinline__ float bf2f(short u) {
  return __uint_as_float(((unsigned int)(unsigned short)u) << 16);
}
__device__ __forceinline__ unsigned short f2bf(float f) {
  unsigned int u = __float_as_uint(f);
  u = u + 0x7FFFu + ((u >> 16) & 1u);   // RNE
  return (unsigned short)(u >> 16);
}

// ---------------- convert fp32 -> bf16 (vectorized, 8 elems/thread) ----------------
__global__ __launch_bounds__(256)
void cvt_f32_bf16(const float* __restrict__ in, unsigned short* __restrict__ out, int n8) {
  int i = blockIdx.x * 256 + threadIdx.x;
  if (i >= n8) return;
  const float4* p = (const float4*)in + (size_t)i * 2;
  float4 a = p[0], b = p[1];
  bf16x8 o;
  o[0] = (short)f2bf(a.x); o[1] = (short)f2bf(a.y); o[2] = (short)f2bf(a.z); o[3] = (short)f2bf(a.w);
  o[4] = (short)f2bf(b.x); o[5] = (short)f2bf(b.y); o[6] = (short)f2bf(b.z); o[7] = (short)f2bf(b.w);
  *((bf16x8*)out + i) = o;
}

// ---------------- transpose + convert: in[K][N] f32 -> out[N][K] bf16 ----------------
__global__ __launch_bounds__(256)
void tcvt(const float* __restrict__ in, unsigned short* __restrict__ out, int K, int N) {
  __shared__ float t[32][33];
  int n0 = blockIdx.x * 32, k0 = blockIdx.y * 32;
  int tx = threadIdx.x & 31, ty = threadIdx.x >> 5;
#pragma unroll
  for (int j = 0; j < 4; ++j)
    t[ty + 8 * j][tx] = in[(size_t)(k0 + ty + 8 * j) * N + n0 + tx];
  __syncthreads();
#pragma unroll
  for (int j = 0; j < 4; ++j)
    out[(size_t)(n0 + ty + 8 * j) * K + k0 + tx] = f2bf(t[tx][ty + 8 * j]);
}

// ================= 256x256 8-phase bf16 MFMA GEMM: C = A(MxK) @ Bt(NxK)^T =================
// LDS per slot (bytes): A_kh0 @0, A_kh1 @16384, B_kh0 @32768, B_kh1 @49152. slot stride 65536.
// Shorts: A_kh0 @0, A_kh1 @8192, B_kh0 @16384, B_kh1 @24576; slot stride 32768.
// kh tile layout: [256 rows][32 shorts], 64B rows, byte-col swizzle ^= ((row>>1)&3)<<4.
// EPI=0: bf16 out, elu+1 on cols < eluCols.  EPI=1: f32 out + bias.
template <int EPI>
__global__ __launch_bounds__(512, 2)
void gemm8p(const unsigned short* __restrict__ A, const unsigned short* __restrict__ Bt,
            void* __restrict__ Cout, const float* __restrict__ bias,
            int M, int N, int K, int eluCols) {
  __shared__ __align__(16) unsigned short lds[65536];   // 128 KiB
  const int tid = threadIdx.x;
  const int wid = tid >> 6, lane = tid & 63;
  const int wr = wid >> 2, wc = wid & 3;                // 2(M) x 4(N) wave grid
  const int fr = lane & 15, fq = lane >> 4;

  // bijective XCD swizzle (nwg % 8 == 0 for all our grids)
  const int nwg = gridDim.x;
  const int q8 = nwg >> 3;
  const int swzid = (blockIdx.x & 7) * q8 + (blockIdx.x >> 3);
  const int mt = M >> 8;
  const int bm = swzid % mt, bn = swzid / mt;
  const int rowA0 = bm << 8, rowB0 = bn << 8;

  // staging geometry: issue = 8KB = 128 rows x 64B; thread -> (row, 16B col)
  const int sr = (wid << 4) + (lane >> 2);              // 0..127 (row within issue)
  const int scb = (lane & 3) << 4;                      // byte col 0/16/32/48
  const int co = (scb ^ (((sr >> 1) & 3) << 4)) >> 1;   // swizzled src elem col (j-invariant)
  const int stW = wid << 9;                             // wave LDS offset in shorts (wid*1024B)

  // per-thread fragment read offsets (shorts) within a kh tile
  int aOff[8], bOff[4];
#pragma unroll
  for (int m = 0; m < 8; ++m) {
    int row = (wr << 7) + (m << 4) + fr;
    aOff[m] = (row << 5) + ((((fq << 4)) ^ (((row >> 1) & 3) << 4)) >> 1);
  }
#pragma unroll
  for (int n = 0; n < 4; ++n) {
    int row = (wc << 6) + (n << 4) + fr;
    bOff[n] = (row << 5) + ((((fq << 4)) ^ (((row >> 1) & 3) << 4)) >> 1);
  }

  f32x4 acc[8][4];
#pragma unroll
  for (int m = 0; m < 8; ++m)
#pragma unroll
    for (int n = 0; n < 4; ++n) acc[m][n] = (f32x4)(0.f);

  auto issue = [&](const unsigned short* __restrict__ G, int row0, int kcol,
                   int ldsShortBase, int j) {
    int r = (j << 7) + sr;
    const unsigned short* src = G + (size_t)(row0 + r) * K + kcol + co;
    __builtin_amdgcn_global_load_lds(
        (const __attribute__((address_space(1))) void*)src,
        (__attribute__((address_space(3))) void*)(lds + ldsShortBase + (j << 12) + stW),
        16, 0, 0);
  };

  const int NT = K >> 6;

  // prologue: stage full tile 0 into slot 0 (order: Akh0 x2, Bkh0 x2, Akh1 x2, Bkh1 x2)
  issue(A, rowA0, 0, 0, 0);          issue(A, rowA0, 0, 0, 1);
  issue(Bt, rowB0, 0, 16384, 0);     issue(Bt, rowB0, 0, 16384, 1);
  issue(A, rowA0, 32, 8192, 0);      issue(A, rowA0, 32, 8192, 1);
  issue(Bt, rowB0, 32, 24576, 0);    issue(Bt, rowB0, 32, 24576, 1);
  asm volatile("s_waitcnt vmcnt(4)" ::: "memory");
  BARRIER();

  bf16x8 a[8];
  for (int t = 0; t < NT; ++t) {
    const int so = (t & 1) << 15;          // this slot (shorts)
    const int sn = ((t + 1) & 1) << 15;    // next slot
    const bool st = (t + 1 < NT);
    const int k1 = (t + 1) << 6;

    // ---- phase A: kk0, n-half0 ----
    {
      const unsigned short* sA = lds + so;
      const unsigned short* sB = lds + so + 16384;
#pragma unroll
      for (int m = 0; m < 8; ++m) a[m] = *(const bf16x8*)(sA + aOff[m]);
      bf16x8 b0 = *(const bf16x8*)(sB + bOff[0]);
      bf16x8 b1 = *(const bf16x8*)(sB + bOff[1]);
      if (st) { issue(A, rowA0, k1, sn, 0); issue(A, rowA0, k1, sn, 1); }
      BARRIER();
      __builtin_amdgcn_s_setprio(1);
#pragma unroll
      for (int m = 0; m < 8; ++m) acc[m][0] = MFMA_BF16(a[m], b0, acc[m][0], 0, 0, 0);
#pragma unroll
      for (int m = 0; m < 8; ++m) acc[m][1] = MFMA_BF16(a[m], b1, acc[m][1], 0, 0, 0);
      __builtin_amdgcn_s_setprio(0);
      BARRIER();
    }
    // ---- phase B: kk0, n-half1 ----
    {
      const unsigned short* sB = lds + so + 16384;
      bf16x8 b2 = *(const bf16x8*)(sB + bOff[2]);
      bf16x8 b3 = *(const bf16x8*)(sB + bOff[3]);
      if (st) { issue(Bt, rowB0, k1, sn + 16384, 0); issue(Bt, rowB0, k1, sn + 16384, 1); }
      BARRIER();
      __builtin_amdgcn_s_setprio(1);
#pragma unroll
      for (int m = 0; m < 8; ++m) acc[m][2] = MFMA_BF16(a[m], b2, acc[m][2], 0, 0, 0);
#pragma unroll
      for (int m = 0; m < 8; ++m) acc[m][3] = MFMA_BF16(a[m], b3, acc[m][3], 0, 0, 0);
      __builtin_amdgcn_s_setprio(0);
      if (st) { asm volatile("s_waitcnt vmcnt(4)" ::: "memory"); }
      else    { asm volatile("s_waitcnt vmcnt(0)" ::: "memory"); }
      BARRIER();
    }
    // ---- phase C: kk1, n-half0 ----
    {
      const unsigned short* sA = lds + so + 8192;
      const unsigned short* sB = lds + so + 24576;
#pragma unroll
      for (int m = 0; m < 8; ++m) a[m] = *(const bf16x8*)(sA + aOff[m]);
      bf16x8 b0 = *(const bf16x8*)(sB + bOff[0]);
      bf16x8 b1 = *(const bf16x8*)(sB + bOff[1]);
      if (st) { issue(A, rowA0, k1 + 32, sn + 8192, 0); issue(A, rowA0, k1 + 32, sn + 8192, 1); }
      BARRIER();
      __builtin_amdgcn_s_setprio(1);
#pragma unroll
      for (int m = 0; m < 8; ++m) acc[m][0] = MFMA_BF16(a[m], b0, acc[m][0], 0, 0, 0);
#pragma unroll
      for (int m = 0; m < 8; ++m) acc[m][1] = MFMA_BF16(a[m], b1, acc[m][1], 0, 0, 0);
      __builtin_amdgcn_s_setprio(0);
      BARRIER();
    }
    // ---- phase D: kk1, n-half1 ----
    {
      const unsigned short* sB = lds + so + 24576;
      bf16x8 b2 = *(const bf16x8*)(sB + bOff[2]);
      bf16x8 b3 = *(const bf16x8*)(sB + bOff[3]);
      if (st) { issue(Bt, rowB0, k1 + 32, sn + 24576, 0); issue(Bt, rowB0, k1 + 32, sn + 24576, 1); }
      BARRIER();
      __builtin_amdgcn_s_setprio(1);
#pragma unroll
      for (int m = 0; m < 8; ++m) acc[m][2] = MFMA_BF16(a[m], b2, acc[m][2], 0, 0, 0);
#pragma unroll
      for (int m = 0; m < 8; ++m) acc[m][3] = MFMA_BF16(a[m], b3, acc[m][3], 0, 0, 0);
      __builtin_amdgcn_s_setprio(0);
      if (st) { asm volatile("s_waitcnt vmcnt(4)" ::: "memory"); }
      BARRIER();
    }
  }

  // ================= epilogue: wave-private LDS transpose -> coalesced 16B stores =================
  const int colBase = rowB0 + (wc << 6);
  const size_t gr0 = (size_t)rowA0 + ((size_t)wr << 7);
  if (EPI == 0) {
    unsigned short* w = lds + (wid << 13);   // 8192 shorts = [128][64] bf16
#pragma unroll
    for (int m = 0; m < 8; ++m)
#pragma unroll
      for (int n = 0; n < 4; ++n) {
        int col = colBase + (n << 4) + fr;
        bool elu = col < eluCols;
#pragma unroll
        for (int r = 0; r < 4; ++r) {
          float x = acc[m][n][r];
          if (elu) x = x > 0.f ? x + 1.f : __expf(x);   // elu(x)+1
          w[(((m << 4) + (fq << 2) + r) << 6) + (n << 4) + fr] = f2bf(x);
        }
      }
    asm volatile("s_waitcnt lgkmcnt(0)" ::: "memory");
    __builtin_amdgcn_sched_barrier(0);
    unsigned short* Cb = (unsigned short*)Cout;
#pragma unroll
    for (int it = 0; it < 16; ++it) {
      int u = (it << 6) + lane;
      int row = u >> 3, cu = u & 7;
      bf16x8 v = *(const bf16x8*)(w + (row << 6) + (cu << 3));
      *(bf16x8*)(Cb + (gr0 + row) * N + colBase + (cu << 3)) = v;
    }
  } else {
    float* wf = (float*)(lds + (wid << 13));  // 4096 floats = [64][64] f32
    float bv[4];
#pragma unroll
    for (int n = 0; n < 4; ++n) bv[n] = bias[colBase + (n << 4) + fr];
    float* Cf = (float*)Cout;
#pragma unroll
    for (int p = 0; p < 2; ++p) {
#pragma unroll
      for (int m = 0; m < 4; ++m)
#pragma unroll
        for (int n = 0; n < 4; ++n)
#pragma unroll
          for (int r = 0; r < 4; ++r)
            wf[(((m << 4) + (fq << 2) + r) << 6) + (n << 4) + fr] = acc[p * 4 + m][n][r] + bv[n];
      asm volatile("s_waitcnt lgkmcnt(0)" ::: "memory");
      __builtin_amdgcn_sched_barrier(0);
#pragma unroll
      for (int it = 0; it < 16; ++it) {
        int u = (it << 6) + lane;
        int row = u >> 4, cu = u & 15;
        f32x4 v = *(const f32x4*)(wf + (row << 6) + (cu << 2));
        *(f32x4*)(Cf + (gr0 + (p << 6) + row) * N + colBase + (cu << 2)) = v;
      }
      if (p == 0) {
        asm volatile("s_waitcnt lgkmcnt(0)" ::: "memory");
        __builtin_amdgcn_sched_barrier(0);
      }
    }
  }
}

// ---------------- kv[b,h,d,e] = sum_s k[s,d]*v[s,e]; ksum[b,h,d] = sum_s k[s,d] ----------------
__global__ __launch_bounds__(256)
void kv_accum(const unsigned short* __restrict__ qkv, float* __restrict__ kv_out,
              float* __restrict__ ksum) {
  const int bh = blockIdx.x;
  const int b = bh / 12, h = bh - b * 12;
  const int s0 = blockIdx.y * SCH;
  __shared__ __align__(16) float ks[SCH][64];
  __shared__ __align__(16) float vs[SCH][64];
  const size_t rowbase = (size_t)(b * 4096 + s0) * 2304;
  const unsigned short* kg = qkv + rowbase + 768 + h * 64;
  const unsigned short* vg = qkv + rowbase + 1536 + h * 64;
  for (int i = threadIdx.x; i < SCH * 8; i += 256) {
    int s = i >> 3, dc = (i & 7) << 3;
    bf16x8 k8 = *(const bf16x8*)(kg + (size_t)s * 2304 + dc);
    bf16x8 v8 = *(const bf16x8*)(vg + (size_t)s * 2304 + dc);
#pragma unroll
    for (int j = 0; j < 8; ++j) {
      ks[s][dc + j] = bf2f(k8[j]);
      vs[s][dc + j] = bf2f(v8[j]);
    }
  }
  __syncthreads();
  const int td = threadIdx.x >> 4, te = threadIdx.x & 15;
  float acc[4][4] = {};
  float ksl[4] = {};
#pragma unroll 4
  for (int s = 0; s < SCH; ++s) {
    f32x4 ka = *(const f32x4*)&ks[s][td * 4];
    f32x4 va = *(const f32x4*)&vs[s][te * 4];
#pragma unroll
    for (int i = 0; i < 4; ++i) {
      ksl[i] += ka[i];
#pragma unroll
      for (int j = 0; j < 4; ++j) acc[i][j] += ka[i] * va[j];
    }
  }
  float* kvp = kv_out + ((size_t)bh * 64 + td * 4) * 64 + te * 4;
#pragma unroll
  for (int i = 0; i < 4; ++i)
#pragma unroll
    for (int j = 0; j < 4; ++j) atomicAdd(&kvp[(size_t)i * 64 + j], acc[i][j]);
  if (te == 0) {
#pragma unroll
    for (int i = 0; i < 4; ++i) atomicAdd(&ksum[bh * 64 + td * 4 + i], ksl[i]);
  }
}

// ---------------- attn[b,s,h*64+e] = z * sum_d q[s,d]*kv[d,e];  z = 1/sum_d q[s,d]*ksum[d] ----------------
__global__ __launch_bounds__(256)
void attn_out(const unsigned short* __restrict__ qkv, const float* __restrict__ kv,
              const float* __restrict__ ksum, unsigned short* __restrict__ attn) {
  const int bh = blockIdx.x;
  const int b = bh / 12, h = bh - b * 12;
  const int s0 = blockIdx.y * 64;
  __shared__ __align__(16) float kvs[64][64];
  __shared__ float kss[64];
  {
    const float4* kvg = (const float4*)(kv + (size_t)bh * 4096);
    float4* kvl = (float4*)&kvs[0][0];
    for (int i = threadIdx.x; i < 1024; i += 256) kvl[i] = kvg[i];
    if (threadIdx.x < 64) kss[threadIdx.x] = ksum[bh * 64 + threadIdx.x];
  }
  __syncthreads();
  const int tr = threadIdx.x >> 2;
  const int te = threadIdx.x & 3;
  const int s = s0 + tr;
  const unsigned short* qg = qkv + (size_t)(b * 4096 + s) * 2304 + h * 64;
  bf16x8 q8[8];
#pragma unroll
  for (int c = 0; c < 8; ++c) q8[c] = *(const bf16x8*)(qg + c * 8);
  float acc[16] = {};
  float zz = 0.f;
#pragma unroll
  for (int c = 0; c < 8; ++c) {
#pragma unroll
    for (int j = 0; j < 8; ++j) {
      const int d = c * 8 + j;
      const float qd = bf2f(q8[c][j]);
      zz += qd * kss[d];
      const f32x4* kvr = (const f32x4*)&kvs[d][te * 16];
#pragma unroll
      for (int q4 = 0; q4 < 4; ++q4) {
        f32x4 kk = kvr[q4];
        acc[q4 * 4 + 0] += qd * kk[0];
        acc[q4 * 4 + 1] += qd * kk[1];
        acc[q4 * 4 + 2] += qd * kk[2];
        acc[q4 * 4 + 3] += qd * kk[3];
      }
    }
  }
  const float z = 1.f / zz;
  bf16x8 o0, o1;
#pragma unroll
  for (int j = 0; j < 8; ++j) o0[j] = (short)f2bf(acc[j] * z);
#pragma unroll
  for (int j = 0; j < 8; ++j) o1[j] = (short)f2bf(acc[8 + j] * z);
  unsigned short* og = attn + (size_t)(b * 4096 + s) * 768 + h * 64 + te * 16;
  *(bf16x8*)og = o0;
  *(bf16x8*)(og + 8) = o1;
}

extern "C" void kernel_launch(void* const* d_in, const int* in_sizes, int n_in,
                              void* d_out, int out_size, void* d_ws, size_t ws_size,
                              hipStream_t stream) {
  const float* x      = (const float*)d_in[0];
  const float* w_qkv  = (const float*)d_in[1];
  const float* w_proj = (const float*)d_in[2];
  const float* b_proj = (const float*)d_in[3];
  const int B = 8, N = 4096, C = 768, H = 12, D = 64;
  const int M = B * N;      // 32768
  const int N1 = 3 * C;     // 2304

  char* ws = (char*)d_ws;
  unsigned short* xb     = (unsigned short*)(ws);               // 50,331,648 B (reused for attn out)
  unsigned short* wqkvT  = (unsigned short*)(ws + 50331648);    //  3,538,944 B
  unsigned short* wprojT = (unsigned short*)(ws + 53870592);    //  1,179,648 B
  float*          ksum   = (float*)(ws + 55050240);             //     24,576 B
  unsigned short* qkvb   = (unsigned short*)(ws + 55074816);    // 150,994,944 B

  float* out_main = (float*)d_out;
  float* kv_out   = out_main + (size_t)M * C;   // kv output: (B,H,D,D) f32

  hipMemsetAsync(kv_out, 0, (size_t)B * H * D * D * sizeof(float), stream);
  hipMemsetAsync(ksum, 0, (size_t)B * H * D * sizeof(float), stream);

  cvt_f32_bf16<<<(M * C / 8 + 255) / 256, 256, 0, stream>>>(x, xb, M * C / 8);
  tcvt<<<dim3(N1 / 32, C / 32), 256, 0, stream>>>(w_qkv, wqkvT, C, N1);
  tcvt<<<dim3(C / 32, C / 32), 256, 0, stream>>>(w_proj, wprojT, C, C);

  // qkv = x @ w_qkv (elu+1 on q,k cols), bf16 out.  grid = (32768/256)*(2304/256) = 128*9 = 1152
  gemm8p<0><<<1152, 512, 0, stream>>>(xb, wqkvT, qkvb, nullptr, M, N1, C, 2 * C);

  // global kv + ksum accumulation (fp32 atomics into zeroed buffers)
  kv_accum<<<dim3(B * H, N / SCH), 256, 0, stream>>>(qkvb, kv_out, ksum);

  // out_attn = (q @ kv) * z, bf16 into xb
  attn_out<<<dim3(B * H, N / 64), 256, 0, stream>>>(qkvb, kv_out, ksum, xb);

  // out = attn @ w_proj + b_proj, fp32.  grid = 128 * 3 = 384
  gemm8p<1><<<384, 512, 0, stream>>>(xb, wprojT, d_out, b_proj, M, C, C, 0);
}

// Round 5
// 517.490 us; speedup vs baseline: 1.2810x; 1.2257x over previous
//
#include <hip/hip_runtime.h>
#include <hip/hip_bf16.h>

typedef short bf16x8 __attribute__((ext_vector_type(8)));
typedef float f32x4 __attribute__((ext_vector_type(4)));

#define MFMA_BF16 __builtin_amdgcn_mfma_f32_16x16x32_bf16
#define BARRIER() asm volatile("s_barrier" ::: "memory")

__device__ __forceinline__ float bf2f(short u) {
  return __uint_as_float(((unsigned int)(unsigned short)u) << 16);
}
__device__ __forceinline__ unsigned short f2bf(float f) {
  unsigned int u = __float_as_uint(f);
  u = u + 0x7FFFu + ((u >> 16) & 1u);   // RNE
  return (unsigned short)(u >> 16);
}

// ---------------- convert fp32 -> bf16 ----------------
__global__ __launch_bounds__(256)
void cvt_f32_bf16(const float* __restrict__ in, unsigned short* __restrict__ out, int n8) {
  int i = blockIdx.x * 256 + threadIdx.x;
  if (i >= n8) return;
  const float4* p = (const float4*)in + (size_t)i * 2;
  float4 a = p[0], b = p[1];
  bf16x8 o;
  o[0] = (short)f2bf(a.x); o[1] = (short)f2bf(a.y); o[2] = (short)f2bf(a.z); o[3] = (short)f2bf(a.w);
  o[4] = (short)f2bf(b.x); o[5] = (short)f2bf(b.y); o[6] = (short)f2bf(b.z); o[7] = (short)f2bf(b.w);
  *((bf16x8*)out + i) = o;
}

// ---------------- transpose + convert: in[K][N] f32 -> out[N][K] bf16 ----------------
__global__ __launch_bounds__(256)
void tcvt(const float* __restrict__ in, unsigned short* __restrict__ out, int K, int N) {
  __shared__ float t[32][33];
  int n0 = blockIdx.x * 32, k0 = blockIdx.y * 32;
  int tx = threadIdx.x & 31, ty = threadIdx.x >> 5;
#pragma unroll
  for (int j = 0; j < 4; ++j)
    t[ty + 8 * j][tx] = in[(size_t)(k0 + ty + 8 * j) * N + n0 + tx];
  __syncthreads();
#pragma unroll
  for (int j = 0; j < 4; ++j)
    out[(size_t)(n0 + ty + 8 * j) * K + k0 + tx] = f2bf(t[tx][ty + 8 * j]);
}

// ============ persistent 3-slot-ring bf16 MFMA GEMM: C = A(32768xK) @ Bt(NxK)^T ============
// BM=256, BN=128, BK=64. grid = 256 blocks (1/CU): bm = bid&127 (256-row stripe),
// g = bid>>7 selects bn-walk [g*NTILES, (g+1)*NTILES). 8 waves (2M x 4N), wave tile 128x32.
// LDS ring: 3 slots x 24576 shorts (A-kh0@0, A-kh1@8192, B-kh0@16384, B-kh1@20480),
// epilogue spare @73728 (512 shorts/wave). Phase = one K-half: 10 ds_read_b128 + 3
// global_load_lds(16B) + 16 MFMA; ONE barrier/phase; steady vmcnt(9) (issue->wait = 4 phases);
// tail waits 9,6,3,0. Row swizzle: byte-col ^= ((row>>1)&3)<<4 (applied at source + read).
template <int EPI, int NTILES>
__global__ __launch_bounds__(512, 1)
void gemmP(const unsigned short* __restrict__ A, const unsigned short* __restrict__ Bt,
           void* __restrict__ Cout, const float* __restrict__ bias,
           int N, int K, int eluCols) {
  __shared__ __align__(16) unsigned short lds[77824];   // 152 KiB
  const int tid = threadIdx.x;
  const int wid = tid >> 6, lane = tid & 63;
  const int wr = wid >> 2, wc = wid & 3;
  const int fr = lane & 15, fq = lane >> 4;
  const int bm = blockIdx.x & 127;
  const int g  = blockIdx.x >> 7;
  const int rowA0 = bm << 8;
  const int bn0 = g * NTILES;

  const int sr  = (wid << 4) + (lane >> 2);             // staging row 0..127
  const int scb = (lane & 3) << 4;                      // staging byte-col
  const int co  = (scb ^ (((sr >> 1) & 3) << 4)) >> 1;  // pre-swizzled src col (shorts)
  const int stW = wid << 9;                             // wave LDS offset (shorts)

  int aOff[8], bOff[2];
#pragma unroll
  for (int m = 0; m < 8; ++m) {
    int row = (wr << 7) + (m << 4) + fr;
    aOff[m] = (row << 5) + (((fq << 4) ^ (((row >> 1) & 3) << 4)) >> 1);
  }
#pragma unroll
  for (int n = 0; n < 2; ++n) {
    int row = (wc << 5) + (n << 4) + fr;
    bOff[n] = (row << 5) + (((fq << 4) ^ (((row >> 1) & 3) << 4)) >> 1);
  }

  auto issueA = [&](int slotS, int h, int j, int kcol) {
    const unsigned short* src = A + (size_t)(rowA0 + (j << 7) + sr) * K + kcol + co;
    __builtin_amdgcn_global_load_lds(
        (const __attribute__((address_space(1))) void*)src,
        (__attribute__((address_space(3))) void*)(lds + slotS + (h << 13) + (j << 12) + stW),
        16, 0, 0);
  };
  auto issueB = [&](int slotS, int h, int kcol, int brow0) {
    const unsigned short* src = Bt + (size_t)(brow0 + sr) * K + kcol + co;
    __builtin_amdgcn_global_load_lds(
        (const __attribute__((address_space(1))) void*)src,
        (__attribute__((address_space(3))) void*)(lds + slotS + 16384 + (h << 12) + stW),
        16, 0, 0);
  };

  const int TOTG = NTILES * 12;
  // prologue: stage G=0,1 (12 issues)
#pragma unroll
  for (int G = 0; G < 2; ++G) {
#pragma unroll
    for (int h = 0; h < 2; ++h) {
      int kcol = (G << 6) + (h << 5);
      issueA(G * 24576, h, 0, kcol);
      issueA(G * 24576, h, 1, kcol);
      issueB(G * 24576, h, kcol, bn0 << 7);
    }
  }

  int ktn = 2, bnn = bn0, sn = 2;   // prefetch target: kt, bn, slot (for G+2)
  int G = 0, slotS = 0;
  const size_t ldc = (size_t)N;

  for (int T = 0; T < NTILES; ++T) {
    f32x4 acc[8][2];
#pragma unroll
    for (int m = 0; m < 8; ++m) { acc[m][0] = (f32x4)(0.f); acc[m][1] = (f32x4)(0.f); }

    for (int kt = 0; kt < 12; ++kt) {
#pragma unroll
      for (int h = 0; h < 2; ++h) {
        // ---- counted wait readying the half read THIS phase ----
        if (G < TOTG - 2)            { asm volatile("s_waitcnt vmcnt(9)" ::: "memory"); }
        else if (G == TOTG - 2) { if (h == 0) asm volatile("s_waitcnt vmcnt(9)" ::: "memory");
                                  else        asm volatile("s_waitcnt vmcnt(6)" ::: "memory"); }
        else                    { if (h == 0) asm volatile("s_waitcnt vmcnt(3)" ::: "memory");
                                  else        asm volatile("s_waitcnt vmcnt(0)" ::: "memory"); }
        BARRIER();
        const unsigned short* sA = lds + slotS + (h << 13);
        const unsigned short* sB = lds + slotS + 16384 + (h << 12);
        bf16x8 av[8];
#pragma unroll
        for (int m = 0; m < 8; ++m) av[m] = *(const bf16x8*)(sA + aOff[m]);
        bf16x8 b0 = *(const bf16x8*)(sB + bOff[0]);
        bf16x8 b1 = *(const bf16x8*)(sB + bOff[1]);
        if (G + 2 < TOTG) {
          int ss = sn * 24576;
          int kcol = (ktn << 6) + (h << 5);
          issueA(ss, h, 0, kcol);
          issueA(ss, h, 1, kcol);
          issueB(ss, h, kcol, bnn << 7);
        }
        __builtin_amdgcn_s_setprio(1);
#pragma unroll
        for (int m = 0; m < 8; ++m) acc[m][0] = MFMA_BF16(av[m], b0, acc[m][0], 0, 0, 0);
#pragma unroll
        for (int m = 0; m < 8; ++m) acc[m][1] = MFMA_BF16(av[m], b1, acc[m][1], 0, 0, 0);
        __builtin_amdgcn_s_setprio(0);
      }
      ++G;
      if (++ktn == 12) { ktn = 0; ++bnn; }
      if (++sn == 3) sn = 0;
      slotS += 24576; if (slotS == 73728) slotS = 0;
    }

    // ---- epilogue for tile T (wave-private spare LDS; no cross-wave barrier) ----
    {
      unsigned short* sp = lds + 73728 + (wid << 9);
      const int bnT = bn0 + T;
      const int colBase = (bnT << 7) + (wc << 5);
      const size_t gr0 = (size_t)rowA0 + ((size_t)wr << 7);
      if (EPI == 0) {
        unsigned short* Cb = (unsigned short*)Cout;
#pragma unroll
        for (int m = 0; m < 8; ++m) {
#pragma unroll
          for (int n = 0; n < 2; ++n) {
            int col = colBase + (n << 4) + fr;
            bool elu = col < eluCols;
#pragma unroll
            for (int r = 0; r < 4; ++r) {
              float x = acc[m][n][r];
              if (elu) x = x > 0.f ? x + 1.f : __expf(x);   // elu(x)+1
              sp[(((fq << 2) + r) << 5) + (n << 4) + fr] = f2bf(x);
            }
          }
          asm volatile("s_waitcnt lgkmcnt(0)" ::: "memory");
          __builtin_amdgcn_sched_barrier(0);
          bf16x8 v = *(const bf16x8*)(sp + (lane << 3));
          *(bf16x8*)(Cb + (gr0 + (m << 4) + (lane >> 2)) * ldc + colBase + ((lane & 3) << 3)) = v;
          asm volatile("s_waitcnt lgkmcnt(0)" ::: "memory");
          __builtin_amdgcn_sched_barrier(0);
        }
      } else {
        float* Cf = (float*)Cout;
        float* spf = (float*)sp;
        float bv[2];
#pragma unroll
        for (int n = 0; n < 2; ++n) bv[n] = bias[colBase + (n << 4) + fr];
#pragma unroll
        for (int m = 0; m < 8; ++m) {
#pragma unroll
          for (int n = 0; n < 2; ++n) {
#pragma unroll
            for (int r = 0; r < 4; ++r)
              spf[(((fq << 2) + r) << 4) + fr] = acc[m][n][r] + bv[n];
            asm volatile("s_waitcnt lgkmcnt(0)" ::: "memory");
            __builtin_amdgcn_sched_barrier(0);
            f32x4 v = *(const f32x4*)(spf + (lane << 2));
            *(f32x4*)(Cf + (gr0 + (m << 4) + (lane >> 2)) * ldc + colBase + (n << 4) + ((lane & 3) << 2)) = v;
            asm volatile("s_waitcnt lgkmcnt(0)" ::: "memory");
            __builtin_amdgcn_sched_barrier(0);
          }
        }
      }
    }
  }
}

// ---------------- kv[b,h,d,e] = sum_s k[s,d]*v[s,e]; ksum[b,h,d] = sum_s k[s,d] ----------------
// s-chunk 512 per block (4 staged sub-chunks of 128), atomics once at end (8-way contention)
__global__ __launch_bounds__(256)
void kv_accum(const unsigned short* __restrict__ qkv, float* __restrict__ kv_out,
              float* __restrict__ ksum) {
  const int bh = blockIdx.x;
  const int b = bh / 12, h = bh - b * 12;
  const int s0 = blockIdx.y * 512;
  __shared__ __align__(16) float ks[128][64];
  __shared__ __align__(16) float vs[128][64];
  const int td = threadIdx.x >> 4, te = threadIdx.x & 15;
  float acc[4][4] = {};
  float ksl[4] = {};
  for (int c = 0; c < 4; ++c) {
    const size_t rowbase = (size_t)(b * 4096 + s0 + c * 128) * 2304;
    const unsigned short* kg = qkv + rowbase + 768 + h * 64;
    const unsigned short* vg = qkv + rowbase + 1536 + h * 64;
    for (int i = threadIdx.x; i < 128 * 8; i += 256) {
      int s = i >> 3, dc = (i & 7) << 3;
      bf16x8 k8 = *(const bf16x8*)(kg + (size_t)s * 2304 + dc);
      bf16x8 v8 = *(const bf16x8*)(vg + (size_t)s * 2304 + dc);
#pragma unroll
      for (int j = 0; j < 8; ++j) {
        ks[s][dc + j] = bf2f(k8[j]);
        vs[s][dc + j] = bf2f(v8[j]);
      }
    }
    __syncthreads();
#pragma unroll 4
    for (int s = 0; s < 128; ++s) {
      f32x4 ka = *(const f32x4*)&ks[s][td * 4];
      f32x4 va = *(const f32x4*)&vs[s][te * 4];
#pragma unroll
      for (int i = 0; i < 4; ++i) {
        ksl[i] += ka[i];
#pragma unroll
        for (int j = 0; j < 4; ++j) acc[i][j] += ka[i] * va[j];
      }
    }
    __syncthreads();
  }
  float* kvp = kv_out + ((size_t)bh * 64 + td * 4) * 64 + te * 4;
#pragma unroll
  for (int i = 0; i < 4; ++i)
#pragma unroll
    for (int j = 0; j < 4; ++j) atomicAdd(&kvp[(size_t)i * 64 + j], acc[i][j]);
  if (te == 0) {
#pragma unroll
    for (int i = 0; i < 4; ++i) atomicAdd(&ksum[bh * 64 + td * 4 + i], ksl[i]);
  }
}

// ---------------- attn[b,s,h*64+e] = z * sum_d q[s,d]*kv[d,e];  z = 1/sum_d q[s,d]*ksum[d] ----------------
__global__ __launch_bounds__(256)
void attn_out(const unsigned short* __restrict__ qkv, const float* __restrict__ kv,
              const float* __restrict__ ksum, unsigned short* __restrict__ attn) {
  const int bh = blockIdx.x;
  const int b = bh / 12, h = bh - b * 12;
  const int s0 = blockIdx.y * 64;
  __shared__ __align__(16) float kvs[64][64];
  __shared__ float kss[64];
  {
    const float4* kvg = (const float4*)(kv + (size_t)bh * 4096);
    float4* kvl = (float4*)&kvs[0][0];
    for (int i = threadIdx.x; i < 1024; i += 256) kvl[i] = kvg[i];
    if (threadIdx.x < 64) kss[threadIdx.x] = ksum[bh * 64 + threadIdx.x];
  }
  __syncthreads();
  const int tr = threadIdx.x >> 2;
  const int te = threadIdx.x & 3;
  const int s = s0 + tr;
  const unsigned short* qg = qkv + (size_t)(b * 4096 + s) * 2304 + h * 64;
  bf16x8 q8[8];
#pragma unroll
  for (int c = 0; c < 8; ++c) q8[c] = *(const bf16x8*)(qg + c * 8);
  float acc[16] = {};
  float zz = 0.f;
#pragma unroll
  for (int c = 0; c < 8; ++c) {
#pragma unroll
    for (int j = 0; j < 8; ++j) {
      const int d = c * 8 + j;
      const float qd = bf2f(q8[c][j]);
      zz += qd * kss[d];
      const f32x4* kvr = (const f32x4*)&kvs[d][te * 16];
#pragma unroll
      for (int q4 = 0; q4 < 4; ++q4) {
        f32x4 kk = kvr[q4];
        acc[q4 * 4 + 0] += qd * kk[0];
        acc[q4 * 4 + 1] += qd * kk[1];
        acc[q4 * 4 + 2] += qd * kk[2];
        acc[q4 * 4 + 3] += qd * kk[3];
      }
    }
  }
  const float z = 1.f / zz;
  bf16x8 o0, o1;
#pragma unroll
  for (int j = 0; j < 8; ++j) o0[j] = (short)f2bf(acc[j] * z);
#pragma unroll
  for (int j = 0; j < 8; ++j) o1[j] = (short)f2bf(acc[8 + j] * z);
  unsigned short* og = attn + (size_t)(b * 4096 + s) * 768 + h * 64 + te * 16;
  *(bf16x8*)og = o0;
  *(bf16x8*)(og + 8) = o1;
}

extern "C" void kernel_launch(void* const* d_in, const int* in_sizes, int n_in,
                              void* d_out, int out_size, void* d_ws, size_t ws_size,
                              hipStream_t stream) {
  const float* x      = (const float*)d_in[0];
  const float* w_qkv  = (const float*)d_in[1];
  const float* w_proj = (const float*)d_in[2];
  const float* b_proj = (const float*)d_in[3];
  const int B = 8, N = 4096, C = 768, H = 12, D = 64;
  const int M = B * N;      // 32768
  const int N1 = 3 * C;     // 2304

  char* ws = (char*)d_ws;
  unsigned short* xb     = (unsigned short*)(ws);               // 50,331,648 B (reused for attn out)
  unsigned short* wqkvT  = (unsigned short*)(ws + 50331648);    //  3,538,944 B
  unsigned short* wprojT = (unsigned short*)(ws + 53870592);    //  1,179,648 B
  float*          ksum   = (float*)(ws + 55050240);             //     24,576 B
  unsigned short* qkvb   = (unsigned short*)(ws + 55074816);    // 150,994,944 B

  float* out_main = (float*)d_out;
  float* kv_out   = out_main + (size_t)M * C;   // kv output: (B,H,D,D) f32

  hipMemsetAsync(kv_out, 0, (size_t)B * H * D * D * sizeof(float), stream);
  hipMemsetAsync(ksum, 0, (size_t)B * H * D * sizeof(float), stream);

  cvt_f32_bf16<<<(M * C / 8 + 255) / 256, 256, 0, stream>>>(x, xb, M * C / 8);
  tcvt<<<dim3(N1 / 32, C / 32), 256, 0, stream>>>(w_qkv, wqkvT, C, N1);
  tcvt<<<dim3(C / 32, C / 32), 256, 0, stream>>>(w_proj, wprojT, C, C);

  // qkv = x @ w_qkv (elu+1 on q,k cols), bf16 out. persistent: 256 blocks x 9 bn-tiles
  gemmP<0, 9><<<256, 512, 0, stream>>>(xb, wqkvT, qkvb, nullptr, N1, C, 2 * C);

  // global kv + ksum accumulation
  kv_accum<<<dim3(B * H, N / 512), 256, 0, stream>>>(qkvb, kv_out, ksum);

  // out_attn = (q @ kv) * z, bf16 into xb
  attn_out<<<dim3(B * H, N / 64), 256, 0, stream>>>(qkvb, kv_out, ksum, xb);

  // out = attn @ w_proj + b_proj, fp32. persistent: 256 blocks x 3 bn-tiles
  gemmP<1, 3><<<256, 512, 0, stream>>>(xb, wprojT, d_out, b_proj, C, C, 0);
}